// Round 7
// baseline (36.385 us; speedup 1.0000x reference)
//
#include <hip/hip_runtime.h>

#define NB 16384
#define NN 31
#define NI 10
#define NOPS 4
#define NPASS 4
#define GB 16
#define TPB 512
#define NWAVES 8
#define NODES_PB (GB * NN)   // 496
#define MAXROWS 576          // >= worst-case padded rows (<=556)
#define MAXTILES 36
#define MAXT_PW 5            // ceil(MAXTILES / NWAVES)
#define STROW 20             // u16 per state row => 40B stride (10n mod 32: 16 bank classes)
#define INVALID_NODE 0xFFFFu

typedef __attribute__((ext_vector_type(8))) short bf16x8_t;
typedef __attribute__((ext_vector_type(4))) float f32x4_t;

// ---- DPP sum over the 16 lanes of a DPP row ----
template <int CTRL>
__device__ __forceinline__ float dppf(float v) {
    return __int_as_float(__builtin_amdgcn_update_dpp(
        0, __float_as_int(v), CTRL, 0xF, 0xF, true));
}
__device__ __forceinline__ float rowsum16(float x) {
    x += dppf<0xB1>(x);     // quad_perm xor1
    x += dppf<0x4E>(x);     // quad_perm xor2
    x += dppf<0x124>(x);    // row_ror:4
    x += dppf<0x128>(x);    // row_ror:8
    return x;
}

__device__ __forceinline__ unsigned short f2bf(float f) {
    unsigned u = __float_as_uint(f);
    u += 0x7FFFu + ((u >> 16) & 1u);   // RNE
    return (unsigned short)(u >> 16);
}
// hardware packed f32->bf16 (RNE)
__device__ __forceinline__ unsigned cvtpk(float lo, float hi) {
    unsigned r;
    asm("v_cvt_pk_bf16_f32 %0, %1, %2" : "=v"(r) : "v"(lo), "v"(hi));
    return r;
}
// bf16 (in u32 half) -> f32, 1 VALU op each
__device__ __forceinline__ float blo(unsigned d) { return __uint_as_float(d << 16); }
__device__ __forceinline__ float bhi(unsigned d) { return __uint_as_float(d & 0xFFFF0000u); }

// K-slot map (A and B must agree; k = 32*s + 8*g + e; g = q on A, bq on B):
//   s in {0,1,2}: (i, j) = (4*s + g, e)   [i>=10 -> zero both sides]
//   s == 3: g=0:(e,8) g=1:(e,9) g=2,e<2:(8+e,8) g=3,e<2:(8+e,9), else zero
// --------------------------------------------------------------------------
// Pre-kernel: build bf16 B-fragments for all 4 ops in d_ws (1024 rows x 16B).
__global__ __launch_bounds__(TPB) void pack_tbl(
    const float* __restrict__ tbl, unsigned short* __restrict__ ws)
{
    int fi = blockIdx.x * TPB + threadIdx.x;   // 0..1023
    if (fi < NOPS * 4 * 64) {
        int lane = fi & 63;
        int step = (fi >> 6) & 3;
        int op   = fi >> 8;
        int bq = lane >> 4, bn = lane & 15;
        unsigned short v[8];
        #pragma unroll
        for (int e = 0; e < 8; ++e) {
            float val = 0.0f;
            if (bn < NI) {
                if (step < 2) {
                    val = tbl[((op * NI + 4 * step + bq) * NI + e) * NI + bn];
                } else if (step == 2) {
                    if (bq < 2) val = tbl[((op * NI + 8 + bq) * NI + e) * NI + bn];
                } else {
                    if (bq < 2)      val = tbl[((op * NI + e) * NI + 8 + bq) * NI + bn];
                    else if (e < 2)  val = tbl[((op * NI + 8 + e) * NI + 8 + (bq - 2)) * NI + bn];
                }
            }
            v[e] = f2bf(val);
        }
        uint4 pk;
        pk.x = (unsigned)v[0] | ((unsigned)v[1] << 16);
        pk.y = (unsigned)v[2] | ((unsigned)v[3] << 16);
        pk.z = (unsigned)v[4] | ((unsigned)v[5] << 16);
        pk.w = (unsigned)v[6] | ((unsigned)v[7] << 16);
        ((uint4*)ws)[fi] = pk;
    }
}

__global__ __launch_bounds__(TPB, 8) void listops_mfma(
    const int* __restrict__ cats, const int* __restrict__ ops,
    const int* __restrict__ lits, const int* __restrict__ left,
    const int* __restrict__ right, const unsigned short* __restrict__ tblPk,
    float* __restrict__ out)
{
    __shared__ __align__(8)  unsigned short st[NODES_PB * STROW];  // 19.4 KB bf16 state
    __shared__ __align__(16) unsigned short Bl[NOPS * 4 * 64 * 8]; // 16 KB B-fragments
    __shared__ unsigned short nodeOfRow[MAXROWS];                  // 1.1 KB
    __shared__ unsigned chLR[NODES_PB];                            // 2.0 KB
    __shared__ int cnt[NOPS], base_[NOPS];
    __shared__ unsigned char tileOpSh[MAXTILES];
    __shared__ int nTilesSh;

    const int tid = threadIdx.x;
    const int wv  = tid >> 6;
    const int l   = tid & 63;
    const int q   = l >> 4;     // 0..3 : k-group
    const int c   = l & 15;     // 0..15: A-row (m) / C-col (n)

    // ---------------- phase 0: LDS init + coalesced table copy ----------------
    if (tid < NOPS) cnt[tid] = 0;
    nodeOfRow[tid] = (unsigned short)INVALID_NODE;
    if (tid < MAXROWS - TPB) nodeOfRow[TPB + tid] = (unsigned short)INVALID_NODE;
    {
        const uint4* wsrc = (const uint4*)tblPk;
        uint4* bdst = (uint4*)&Bl[0];
        bdst[tid]       = wsrc[tid];
        bdst[tid + TPB] = wsrc[tid + TPB];
    }
    __syncthreads();   // cnt zeroed before any atomicAdd

    // ---------------- phase 1: metadata, state init, op counting ----------------
    int myRank = -1, myOp = 0;
    if (tid < NODES_PB) {
        int g   = blockIdx.x * NODES_PB + tid;   // coalesced
        int cat = cats[g];
        myOp    = min(max(ops[g], 0), NOPS - 1);
        int lit = min(max(lits[g], 0), NI - 1);
        int bl  = tid / NN;
        int cl  = bl * NN + min(max(left[g],  0), NN - 1);
        int cr  = bl * NN + min(max(right[g], 0), NN - 1);
        chLR[tid] = (unsigned)(cl * (STROW * 2)) | ((unsigned)(cr * (STROW * 2)) << 16);
        unsigned* rp = (unsigned*)&st[tid * STROW];
        rp[0] = 0u; rp[1] = 0u; rp[2] = 0u; rp[3] = 0u; rp[4] = 0u;
        if (cat == 0) {
            st[tid * STROW + lit] = (unsigned short)0x3F80;   // bf16 1.0
            if (tid == bl * NN) {                // literal root: output now
                float* o = out + (blockIdx.x * GB + bl) * NI;
                #pragma unroll
                for (int k = 0; k < NI; ++k) o[k] = (k == lit) ? 10.0f : 0.0f;
            }
        } else {
            myRank = atomicAdd(&cnt[myOp], 1);
        }
    }
    __syncthreads();

    if (tid == 0) {   // serial op-group layout (tiny)
        int rb = 0, t = 0;
        #pragma unroll
        for (int o = 0; o < NOPS; ++o) {
            base_[o] = rb;
            int nt = (cnt[o] + 15) >> 4;
            for (int i = 0; i < nt; ++i) tileOpSh[t++] = (unsigned char)o;
            rb += nt << 4;
        }
        nTilesSh = t;
    }
    __syncthreads();
    if (myRank >= 0) nodeOfRow[base_[myOp] + myRank] = (unsigned short)tid;
    __syncthreads();

    const int nTiles = nTilesSh;

    // ---- hoist pass-invariant per-slot data (ops packed 2b each into one reg) ----
    unsigned slotLR[MAXT_PW];
    unsigned slotOps = 0;
    #pragma unroll
    for (int i = 0; i < MAXT_PW; ++i) {
        slotLR[i] = 0;
        int t = wv + NWAVES * i;
        if (t < nTiles) {
            int node = nodeOfRow[t * 16 + c];
            int nd0  = (node == (int)INVALID_NODE) ? 0 : node;  // pad rows read node 0 (finite, masked later)
            slotLR[i] = chLR[nd0];
            slotOps  |= ((unsigned)tileOpSh[t]) << (2 * i);     // tile's op (NOT the pad row's!)
        }
    }

    f32x4_t acc[MAXT_PW];

    for (int pass = 0; pass < NPASS; ++pass) {
        const bool last = (pass == NPASS - 1);

        // ============ phase A: per-lane A-frags in registers + 4 MFMA ============
        #pragma unroll
        for (int i = 0; i < MAXT_PW; ++i) {
            int t = wv + NWAVES * i;
            if (t < nTiles) {
                unsigned lrp = slotLR[i];
                const char* sbb = (const char*)&st[0];
                const char* Lp = sbb + (lrp & 0xFFFFu);
                const char* Rp = sbb + (lrp >> 16);
                uint2    la = *(const uint2*)Lp;            // {L0L1, L2L3}
                uint2    lb = *(const uint2*)(Lp + 8);      // {L4L5, L6L7}
                unsigned lc = *(const unsigned*)(Lp + 16);  // {L8L9}
                uint2    ra = *(const uint2*)Rp;
                uint2    rb = *(const uint2*)(Rp + 8);
                unsigned rc = *(const unsigned*)(Rp + 16);

                float Re[10] = {blo(ra.x), bhi(ra.x), blo(ra.y), bhi(ra.y),
                                blo(rb.x), bhi(rb.x), blo(rb.y), bhi(rb.y),
                                blo(rc),   bhi(rc)};
                float Le[10] = {blo(la.x), bhi(la.x), blo(la.y), bhi(la.y),
                                blo(lb.x), bhi(lb.x), blo(lb.y), bhi(lb.y),
                                blo(lc),   bhi(lc)};

                // q-dependent L scalars via value selects (no strided LDS reads)
                float lq0 = (q & 1) ? ((q & 2) ? Le[3] : Le[1]) : ((q & 2) ? Le[2] : Le[0]);
                float lq1 = (q & 1) ? ((q & 2) ? Le[7] : Le[5]) : ((q & 2) ? Le[6] : Le[4]);
                float lq2 = (q == 0) ? Le[8] : ((q == 1) ? Le[9] : 0.0f);

                bf16x8_t av0, av1, av2, av3;
                unsigned* a0 = (unsigned*)&av0;
                unsigned* a1 = (unsigned*)&av1;
                unsigned* a2 = (unsigned*)&av2;
                unsigned* a3 = (unsigned*)&av3;
                #pragma unroll
                for (int d = 0; d < 4; ++d) {
                    a0[d] = cvtpk(lq0 * Re[2 * d], lq0 * Re[2 * d + 1]);
                    a1[d] = cvtpk(lq1 * Re[2 * d], lq1 * Re[2 * d + 1]);
                    a2[d] = cvtpk(lq2 * Re[2 * d], lq2 * Re[2 * d + 1]);
                }
                // patch step s=3 (covers j=8,9)
                float rsel = (q & 1) ? Re[9] : Re[8];
                const bool qlo = (q < 2);
                float w3[8];
                w3[0] = (qlo ? Le[0] : Le[8]) * rsel;
                w3[1] = (qlo ? Le[1] : Le[9]) * rsel;
                #pragma unroll
                for (int e = 2; e < 8; ++e) w3[e] = (qlo ? Le[e] : 0.0f) * rsel;
                #pragma unroll
                for (int d = 0; d < 4; ++d)
                    a3[d] = cvtpk(w3[2 * d], w3[2 * d + 1]);

                const char* Bp = (const char*)&Bl[0]
                               + ((slotOps >> (2 * i)) & 3u) * 4096u + l * 16;
                f32x4_t a = {0.0f, 0.0f, 0.0f, 0.0f};
                a = __builtin_amdgcn_mfma_f32_16x16x32_bf16(av0, *(const bf16x8_t*)(Bp + 0 * 1024), a, 0, 0, 0);
                a = __builtin_amdgcn_mfma_f32_16x16x32_bf16(av1, *(const bf16x8_t*)(Bp + 1 * 1024), a, 0, 0, 0);
                a = __builtin_amdgcn_mfma_f32_16x16x32_bf16(av2, *(const bf16x8_t*)(Bp + 2 * 1024), a, 0, 0, 0);
                a = __builtin_amdgcn_mfma_f32_16x16x32_bf16(av3, *(const bf16x8_t*)(Bp + 3 * 1024), a, 0, 0, 0);
                acc[i] = a;
            }
        }

        if (!last) {
            __syncthreads();   // all state reads of this pass done
            // ===== phase B: softmax (no max-sub: |logits| <= max|T| < 0.6) =====
            #pragma unroll
            for (int i = 0; i < MAXT_PW; ++i) {
                int t = wv + NWAVES * i;
                if (t < nTiles) {
                    f32x4_t a = acc[i];
                    ushort4 nds = *(const ushort4*)&nodeOfRow[t * 16 + 4 * q];
                    const unsigned short* np = (const unsigned short*)&nds;
                    #pragma unroll
                    for (int r = 0; r < 4; ++r) {
                        float ex = (c < NI) ? __expf(a[r]) : 0.0f;
                        float sd = rowsum16(ex);
                        float pv = ex * __builtin_amdgcn_rcpf(sd);
                        unsigned short nd = np[r];
                        if (nd != (unsigned short)INVALID_NODE && c < NI) {
                            unsigned pk = cvtpk(pv, pv);
                            st[(unsigned)nd * STROW + c] = (unsigned short)pk;
                        }
                    }
                }
            }
            __syncthreads();   // new state visible
        } else {
            // ============== last pass: emit op-root raw logits ==============
            #pragma unroll
            for (int i = 0; i < MAXT_PW; ++i) {
                int t = wv + NWAVES * i;
                if (t < nTiles) {
                    f32x4_t a = acc[i];
                    ushort4 nds = *(const ushort4*)&nodeOfRow[t * 16 + 4 * q];
                    const unsigned short* np = (const unsigned short*)&nds;
                    #pragma unroll
                    for (int r = 0; r < 4; ++r) {
                        int nd = np[r];
                        if (nd != (int)INVALID_NODE && c < NI) {
                            int bl = nd / NN;
                            if (nd == bl * NN) {   // node 0 of its batch
                                out[(blockIdx.x * GB + bl) * NI + c] = a[r];
                            }
                        }
                    }
                }
            }
        }
    }
}

extern "C" void kernel_launch(void* const* d_in, const int* in_sizes, int n_in,
                              void* d_out, int out_size, void* d_ws, size_t ws_size,
                              hipStream_t stream) {
    const int*   cats     = (const int*)  d_in[0];
    const int*   ops      = (const int*)  d_in[1];
    const int*   lits     = (const int*)  d_in[2];
    const int*   left     = (const int*)  d_in[3];
    const int*   right    = (const int*)  d_in[4];
    // d_in[5] = mask (all true) — unused
    const float* op_table = (const float*)d_in[6];
    float*       out      = (float*)      d_out;
    unsigned short* tblPk = (unsigned short*)d_ws;   // 16 KB packed B-fragments

    hipLaunchKernelGGL(pack_tbl, dim3(2), dim3(TPB), 0, stream, op_table, tblPk);
    hipLaunchKernelGGL(listops_mfma, dim3(NB / GB), dim3(TPB), 0, stream,
                       cats, ops, lits, left, right, tblPk, out);
}

// Round 8
// 31.017 us; speedup vs baseline: 1.1731x; 1.1731x over previous
//
#include <hip/hip_runtime.h>

#define NB 16384
#define NN 31
#define NI 10
#define NOPS 4
#define NPASS 4
#define GB 32
#define TPB 1024
#define NWAVES 16
#define NODES_PB (GB * NN)   // 992
#define MAXROWS 1056         // >= worst-case padded rows (<=65*16=1040)
#define MAXTILES 68
#define MAXT_PW 5            // ceil(65/16)
#define INVALID_NODE 0xFFFFu

typedef __attribute__((ext_vector_type(8))) short bf16x8_t;
typedef __attribute__((ext_vector_type(4))) float f32x4_t;

// ---- DPP sum over the 16 lanes of a DPP row ----
template <int CTRL>
__device__ __forceinline__ float dppf(float v) {
    return __int_as_float(__builtin_amdgcn_update_dpp(
        0, __float_as_int(v), CTRL, 0xF, 0xF, true));
}
__device__ __forceinline__ float rowsum16(float x) {
    x += dppf<0xB1>(x);     // quad_perm xor1
    x += dppf<0x4E>(x);     // quad_perm xor2
    x += dppf<0x124>(x);    // row_ror:4
    x += dppf<0x128>(x);    // row_ror:8
    return x;
}

__device__ __forceinline__ unsigned short f2bf(float f) {
    unsigned u = __float_as_uint(f);
    u += 0x7FFFu + ((u >> 16) & 1u);   // RNE
    return (unsigned short)(u >> 16);
}
// hardware packed f32->bf16 (RNE)
__device__ __forceinline__ unsigned cvtpk(float lo, float hi) {
    unsigned r;
    asm("v_cvt_pk_bf16_f32 %0, %1, %2" : "=v"(r) : "v"(lo), "v"(hi));
    return r;
}

// K-slot map (A and B must agree; k = 32*s + 8*g + e; g = q on A, bq on B):
//   s in {0,1,2}: (i, j) = (4*s + g, e)   [i>=10 -> zero both sides]
//   s == 3: g=0:(e,8) g=1:(e,9) g=2,e<2:(8+e,8) g=3,e<2:(8+e,9), else zero
__global__ __launch_bounds__(TPB, 8) void listops_mfma(
    const int* __restrict__ cats, const int* __restrict__ ops,
    const int* __restrict__ lits, const int* __restrict__ left,
    const int* __restrict__ right, const float* __restrict__ tbl,
    float* __restrict__ out)
{
    __shared__ __align__(16) float st[NODES_PB][12];               // 47.6 KB (cols 10,11 stay 0)
    __shared__ __align__(16) unsigned short Bl[NOPS * 4 * 64 * 8]; // 16 KB B-fragments
    __shared__ unsigned short nodeOfRow[MAXROWS];                  // 2.1 KB
    __shared__ unsigned chLR[NODES_PB];                            // 4.0 KB
    __shared__ int cnt[NOPS], base_[NOPS];
    __shared__ int wbase[NWAVES][NOPS];                            // per-wave op bases
    __shared__ unsigned char tileOpSh[MAXTILES];
    __shared__ int nTilesSh;

    const int tid = threadIdx.x;
    const int wv  = tid >> 6;
    const int l   = tid & 63;
    const int q   = l >> 4;     // 0..3 : k-group
    const int c   = l & 15;     // 0..15: A-row (m) / C-col (n)

    // -------- phase 0: LDS init + in-kernel B-fragment staging (1 row/thread) ----
    if (tid < NOPS) cnt[tid] = 0;
    if (tid < MAXROWS) nodeOfRow[tid] = (unsigned short)INVALID_NODE;
    if (tid < MAXROWS - TPB) nodeOfRow[TPB + tid] = (unsigned short)INVALID_NODE;
    {
        const int fi   = tid;            // 0..1023 == exactly NOPS*4*64 rows
        const int lane = fi & 63;
        const int step = (fi >> 6) & 3;
        const int op   = fi >> 8;
        const int bq = lane >> 4, bn = lane & 15;
        unsigned short v[8];
        #pragma unroll
        for (int e = 0; e < 8; ++e) {
            float val = 0.0f;
            if (bn < NI) {
                if (step < 2) {
                    val = tbl[((op * NI + 4 * step + bq) * NI + e) * NI + bn];
                } else if (step == 2) {
                    if (bq < 2) val = tbl[((op * NI + 8 + bq) * NI + e) * NI + bn];
                } else {
                    if (bq < 2)      val = tbl[((op * NI + e) * NI + 8 + bq) * NI + bn];
                    else if (e < 2)  val = tbl[((op * NI + 8 + e) * NI + 8 + (bq - 2)) * NI + bn];
                }
            }
            v[e] = f2bf(val);
        }
        uint4 pk;
        pk.x = (unsigned)v[0] | ((unsigned)v[1] << 16);
        pk.y = (unsigned)v[2] | ((unsigned)v[3] << 16);
        pk.z = (unsigned)v[4] | ((unsigned)v[5] << 16);
        pk.w = (unsigned)v[6] | ((unsigned)v[7] << 16);
        ((uint4*)&Bl[0])[fi] = pk;
    }
    __syncthreads();   // cnt zeroed before any atomicAdd

    // -------- phase 1: metadata, state init, ballot-based op ranking ------------
    bool isOp = false;
    int  myOp = 0;
    if (tid < NODES_PB) {
        int g   = blockIdx.x * NODES_PB + tid;   // coalesced
        int cat = cats[g];
        myOp    = min(max(ops[g], 0), NOPS - 1);
        int lit = min(max(lits[g], 0), NI - 1);
        int bl  = tid / NN;
        int cl  = bl * NN + min(max(left[g],  0), NN - 1);
        int cr  = bl * NN + min(max(right[g], 0), NN - 1);
        chLR[tid] = (unsigned)(cl * 48) | ((unsigned)(cr * 48) << 16);
        float4* rp = (float4*)&st[tid][0];
        rp[0] = make_float4(0.f, 0.f, 0.f, 0.f);
        rp[1] = make_float4(0.f, 0.f, 0.f, 0.f);
        rp[2] = make_float4(0.f, 0.f, 0.f, 0.f);
        if (cat == 0) {
            st[tid][lit] = 1.0f;
            if (tid == bl * NN) {                // literal root: output now
                float* o = out + (blockIdx.x * GB + bl) * NI;
                #pragma unroll
                for (int k = 0; k < NI; ++k) o[k] = (k == lit) ? 10.0f : 0.0f;
            }
        } else {
            isOp = true;
        }
    }
    // ballot-based ranking: 4 ballots/wave + 4 leader atomics (no 992-way contention)
    int intra = 0;
    {
        const unsigned long long below = (1ull << l) - 1ull;
        #pragma unroll
        for (int o = 0; o < NOPS; ++o) {
            unsigned long long m = __ballot(isOp && (myOp == o));
            if (isOp && myOp == o) intra = __popcll(m & below);
            if (l == 0) wbase[wv][o] = atomicAdd(&cnt[o], __popcll(m));
        }
    }
    __syncthreads();

    if (tid == 0) {   // serial op-group layout (tiny)
        int rb = 0, t = 0;
        #pragma unroll
        for (int o = 0; o < NOPS; ++o) {
            base_[o] = rb;
            int nt = (cnt[o] + 15) >> 4;
            for (int i = 0; i < nt; ++i) tileOpSh[t++] = (unsigned char)o;
            rb += nt << 4;
        }
        nTilesSh = t;
    }
    __syncthreads();
    if (isOp) nodeOfRow[base_[myOp] + wbase[wv][myOp] + intra] = (unsigned short)tid;
    __syncthreads();

    const int nTiles = nTilesSh;

    // ---- hoist pass-invariant per-slot data (ops packed 2b each into one reg) ----
    unsigned slotLR[MAXT_PW];
    unsigned slotOps = 0;
    #pragma unroll
    for (int i = 0; i < MAXT_PW; ++i) {
        slotLR[i] = 0;
        int t = wv + NWAVES * i;
        if (t < nTiles) {
            int node = nodeOfRow[t * 16 + c];
            int nd0  = (node == (int)INVALID_NODE) ? 0 : node;  // pad rows read node 0 (finite, masked later)
            slotLR[i] = chLR[nd0];
            slotOps  |= ((unsigned)tileOpSh[t]) << (2 * i);
        }
    }

    f32x4_t acc[MAXT_PW];

    for (int pass = 0; pass < NPASS; ++pass) {
        const bool last = (pass == NPASS - 1);

        // ============ phase A: per-lane A-frags in registers + 4 MFMA ============
        #pragma unroll
        for (int i = 0; i < MAXT_PW; ++i) {
            int t = wv + NWAVES * i;
            if (t < nTiles) {
                const char* sb = (const char*)&st[0][0];
                unsigned lrp = slotLR[i];
                const float* Lb = (const float*)(sb + (lrp & 0xFFFFu));
                const float* Rb = (const float*)(sb + (lrp >> 16));
                float4 l0  = ((const float4*)Lb)[0];
                float4 l1  = ((const float4*)Lb)[1];
                float2 l89 = ((const float2*)Lb)[4];   // L[8], L[9]
                float4 r0  = ((const float4*)Rb)[0];
                float4 r1  = ((const float4*)Rb)[1];
                float2 r89 = ((const float2*)Rb)[4];   // R[8], R[9]

                // q-dependent L scalars via value selects (no strided LDS reads)
                float lq0 = (q & 2) ? ((q & 1) ? l0.w : l0.z) : ((q & 1) ? l0.y : l0.x);
                float lq1 = (q & 2) ? ((q & 1) ? l1.w : l1.z) : ((q & 1) ? l1.y : l1.x);
                float lq2 = (q == 0) ? l89.x : ((q == 1) ? l89.y : 0.0f);

                float Re[8] = {r0.x, r0.y, r0.z, r0.w, r1.x, r1.y, r1.z, r1.w};
                float Le[8] = {l0.x, l0.y, l0.z, l0.w, l1.x, l1.y, l1.z, l1.w};

                bf16x8_t av0, av1, av2, av3;
                unsigned* a0 = (unsigned*)&av0;
                unsigned* a1 = (unsigned*)&av1;
                unsigned* a2 = (unsigned*)&av2;
                unsigned* a3 = (unsigned*)&av3;
                #pragma unroll
                for (int d = 0; d < 4; ++d) {
                    a0[d] = cvtpk(lq0 * Re[2 * d], lq0 * Re[2 * d + 1]);
                    a1[d] = cvtpk(lq1 * Re[2 * d], lq1 * Re[2 * d + 1]);
                    a2[d] = cvtpk(lq2 * Re[2 * d], lq2 * Re[2 * d + 1]);
                }
                // patch step s=3 (covers j=8,9)
                float rsel = (q & 1) ? r89.y : r89.x;
                const bool qlo = (q < 2);
                float w3[8];
                w3[0] = (qlo ? Le[0] : l89.x) * rsel;
                w3[1] = (qlo ? Le[1] : l89.y) * rsel;
                #pragma unroll
                for (int e = 2; e < 8; ++e) w3[e] = (qlo ? Le[e] : 0.0f) * rsel;
                #pragma unroll
                for (int d = 0; d < 4; ++d)
                    a3[d] = cvtpk(w3[2 * d], w3[2 * d + 1]);

                const char* Bp = (const char*)&Bl[0]
                               + ((slotOps >> (2 * i)) & 3u) * 4096u + l * 16;
                f32x4_t a = {0.0f, 0.0f, 0.0f, 0.0f};
                a = __builtin_amdgcn_mfma_f32_16x16x32_bf16(av0, *(const bf16x8_t*)(Bp + 0 * 1024), a, 0, 0, 0);
                a = __builtin_amdgcn_mfma_f32_16x16x32_bf16(av1, *(const bf16x8_t*)(Bp + 1 * 1024), a, 0, 0, 0);
                a = __builtin_amdgcn_mfma_f32_16x16x32_bf16(av2, *(const bf16x8_t*)(Bp + 2 * 1024), a, 0, 0, 0);
                a = __builtin_amdgcn_mfma_f32_16x16x32_bf16(av3, *(const bf16x8_t*)(Bp + 3 * 1024), a, 0, 0, 0);
                acc[i] = a;
            }
        }

        if (!last) {
            __syncthreads();   // all state reads of this pass done
            // ===== phase B: softmax (no max-sub: |logits| <= max|T| < 0.6) =====
            #pragma unroll
            for (int i = 0; i < MAXT_PW; ++i) {
                int t = wv + NWAVES * i;
                if (t < nTiles) {
                    f32x4_t a = acc[i];
                    ushort4 nds = *(const ushort4*)&nodeOfRow[t * 16 + 4 * q];
                    const unsigned short* np = (const unsigned short*)&nds;
                    #pragma unroll
                    for (int r = 0; r < 4; ++r) {
                        float ex = (c < NI) ? __expf(a[r]) : 0.0f;
                        float sd = rowsum16(ex);
                        float pv = ex * __builtin_amdgcn_rcpf(sd);
                        unsigned short nd = np[r];
                        if (nd != (unsigned short)INVALID_NODE && c < NI)
                            st[nd][c] = pv;
                    }
                }
            }
            __syncthreads();   // new state visible
        } else {
            // ============== last pass: emit op-root raw logits ==============
            #pragma unroll
            for (int i = 0; i < MAXT_PW; ++i) {
                int t = wv + NWAVES * i;
                if (t < nTiles) {
                    f32x4_t a = acc[i];
                    ushort4 nds = *(const ushort4*)&nodeOfRow[t * 16 + 4 * q];
                    const unsigned short* np = (const unsigned short*)&nds;
                    #pragma unroll
                    for (int r = 0; r < 4; ++r) {
                        int nd = np[r];
                        if (nd != (int)INVALID_NODE && c < NI) {
                            int bl = nd / NN;
                            if (nd == bl * NN) {   // node 0 of its batch
                                out[(blockIdx.x * GB + bl) * NI + c] = a[r];
                            }
                        }
                    }
                }
            }
        }
    }
}

extern "C" void kernel_launch(void* const* d_in, const int* in_sizes, int n_in,
                              void* d_out, int out_size, void* d_ws, size_t ws_size,
                              hipStream_t stream) {
    const int*   cats     = (const int*)  d_in[0];
    const int*   ops      = (const int*)  d_in[1];
    const int*   lits     = (const int*)  d_in[2];
    const int*   left     = (const int*)  d_in[3];
    const int*   right    = (const int*)  d_in[4];
    // d_in[5] = mask (all true) — unused
    const float* op_table = (const float*)d_in[6];
    float*       out      = (float*)      d_out;

    hipLaunchKernelGGL(listops_mfma, dim3(NB / GB), dim3(TPB), 0, stream,
                       cats, ops, lits, left, right, op_table, out);
}